// Round 3
// baseline (25.281 us; speedup 1.0000x reference)
//
#include <hip/hip_runtime.h>
#include <hip/hip_bf16.h>

// Embedding gather: out[t, :] = W[ids[t], :]
// ids: [16384] int32, W: [50257, 1024] fp32, out: [16384, 1024] fp32.
// 4 token rows per 256-thread block: each thread issues 4 independent
// float4 gathers (4x memory-level parallelism to hide HBM latency),
// then 4 nontemporal streaming stores (out has no reuse; keep L2 for W).
typedef float f4 __attribute__((ext_vector_type(4)));   // native vec: OK for nontemporal builtin

constexpr int ROWS_PER_BLOCK = 4;
constexpr int ROW_F4 = 256;   // 1024 floats = 256 float4 per row

__global__ __launch_bounds__(256) void Embedding_88227218195299_kernel(
    const int* __restrict__ ids,
    const f4* __restrict__ W,
    f4* __restrict__ out,
    int n_tokens)
{
    int base = blockIdx.x * ROWS_PER_BLOCK;
    int t = threadIdx.x;

    if (base + ROWS_PER_BLOCK <= n_tokens) {
        // fast path: 4 independent gathers in flight
        int i0 = ids[base + 0];
        int i1 = ids[base + 1];
        int i2 = ids[base + 2];
        int i3 = ids[base + 3];
        f4 a = W[(size_t)i0 * ROW_F4 + t];
        f4 b = W[(size_t)i1 * ROW_F4 + t];
        f4 c = W[(size_t)i2 * ROW_F4 + t];
        f4 d = W[(size_t)i3 * ROW_F4 + t];
        __builtin_nontemporal_store(a, &out[(size_t)(base + 0) * ROW_F4 + t]);
        __builtin_nontemporal_store(b, &out[(size_t)(base + 1) * ROW_F4 + t]);
        __builtin_nontemporal_store(c, &out[(size_t)(base + 2) * ROW_F4 + t]);
        __builtin_nontemporal_store(d, &out[(size_t)(base + 3) * ROW_F4 + t]);
    } else {
        for (int r = base; r < n_tokens; ++r) {
            int tok = ids[r];
            f4 v = W[(size_t)tok * ROW_F4 + t];
            __builtin_nontemporal_store(v, &out[(size_t)r * ROW_F4 + t]);
        }
    }
}

extern "C" void kernel_launch(void* const* d_in, const int* in_sizes, int n_in,
                              void* d_out, int out_size, void* d_ws, size_t ws_size,
                              hipStream_t stream) {
    const int*   ids = (const int*)d_in[0];
    const float* W   = (const float*)d_in[1];
    float*       out = (float*)d_out;

    const int n_tokens = in_sizes[0];          // 4 * 4096 = 16384

    dim3 grid((n_tokens + ROWS_PER_BLOCK - 1) / ROWS_PER_BLOCK);  // 4096
    dim3 block(256);
    Embedding_88227218195299_kernel<<<grid, block, 0, stream>>>(
        ids,
        (const f4*)W,
        (f4*)out,
        n_tokens);
}

// Round 4
// 25.221 us; speedup vs baseline: 1.0024x; 1.0024x over previous
//
#include <hip/hip_runtime.h>
#include <hip/hip_bf16.h>

// Embedding gather: out[t, :] = W[ids[t], :]
// ids: [16384] int32, W: [50257, 1024] fp32, out: [16384, 1024] fp32.
//
// One WAVE (64 lanes) per token row: each lane issues 4 independent
// float4 loads covering the row's 4 KB as one tight burst from a single
// wave (DRAM page locality: the whole row is fetched back-to-back instead
// of split across 4 waves on 4 SIMDs). Stores are nontemporal (out has no
// reuse; don't evict W from L2/L3).
typedef float f4 __attribute__((ext_vector_type(4)));

constexpr int ROW_F4 = 256;          // 1024 floats = 256 float4 per row
constexpr int WAVES_PER_BLOCK = 4;   // 256 threads

__global__ __launch_bounds__(256) void Embedding_88227218195299_kernel(
    const int* __restrict__ ids,
    const f4* __restrict__ W,
    f4* __restrict__ out,
    int n_tokens)
{
    int wave = threadIdx.x >> 6;
    int lane = threadIdx.x & 63;
    int row  = blockIdx.x * WAVES_PER_BLOCK + wave;
    if (row >= n_tokens) return;

    int tok = ids[row];                        // wave-uniform -> scalar load
    const f4* __restrict__ src = W   + (size_t)tok * ROW_F4;
    f4* __restrict__       dst = out + (size_t)row * ROW_F4;

    // 4 independent 1 KB wave-loads = the full 4 KB row in one burst.
    f4 a = src[lane +   0];
    f4 b = src[lane +  64];
    f4 c = src[lane + 128];
    f4 d = src[lane + 192];
    __builtin_nontemporal_store(a, &dst[lane +   0]);
    __builtin_nontemporal_store(b, &dst[lane +  64]);
    __builtin_nontemporal_store(c, &dst[lane + 128]);
    __builtin_nontemporal_store(d, &dst[lane + 192]);
}

extern "C" void kernel_launch(void* const* d_in, const int* in_sizes, int n_in,
                              void* d_out, int out_size, void* d_ws, size_t ws_size,
                              hipStream_t stream) {
    const int*   ids = (const int*)d_in[0];
    const float* W   = (const float*)d_in[1];
    float*       out = (float*)d_out;

    const int n_tokens = in_sizes[0];          // 4 * 4096 = 16384

    dim3 grid((n_tokens + WAVES_PER_BLOCK - 1) / WAVES_PER_BLOCK);  // 4096
    dim3 block(256);
    Embedding_88227218195299_kernel<<<grid, block, 0, stream>>>(
        ids,
        (const f4*)W,
        (f4*)out,
        n_tokens);
}